// Round 7
// baseline (455.759 us; speedup 1.0000x reference)
//
#include <hip/hip_runtime.h>
#include <hip/hip_bf16.h>

#define IN_CH 512
#define OUT_CH 64
#define G_PART 128        // edge partitions
#define NQUAD 4           // node quadrants (histo/fill LDS = NW/4 words = 25KB)
#define NWQ_MAX 6272      // LDS words per quadrant: ceil(ceil(N/4)/4), N<=100352
#define BM 64             // gemm rows per block
#define BK 64             // gemm K-chunk (floats)

typedef __attribute__((ext_vector_type(8))) short short8;
typedef __attribute__((ext_vector_type(4))) float f32x4;

static __device__ __forceinline__ unsigned short bf16bits(float f) {
    __hip_bfloat16 h = __float2bfloat16(f);
    return *reinterpret_cast<unsigned short*>(&h);
}
static __device__ __forceinline__ float bflo(unsigned int u) {  // low ushort as bf16 -> f32
    return __uint_as_float(u << 16);
}
static __device__ __forceinline__ float bfhi(unsigned int u) {  // high ushort as bf16 -> f32
    return __uint_as_float(u & 0xffff0000u);
}

// --- prep: W[512][64] -> Wt[64][512] bf16; sentinel hs row N, dinv[N]=0, gcount=0 ---
__global__ void prep_kernel(const float* __restrict__ W, unsigned short* __restrict__ Wt,
                            unsigned short* __restrict__ hs, float* __restrict__ dinv,
                            unsigned int* __restrict__ gcount, int N) {
    int b = blockIdx.x;
    if (b < 128) {
        int i = b * 256 + threadIdx.x;   // 32768
        int k = i >> 6, n = i & 63;
        Wt[n * IN_CH + k] = bf16bits(W[i]);
        return;
    }
    if (threadIdx.x < OUT_CH) hs[(size_t)N * OUT_CH + threadIdx.x] = 0;
    if (threadIdx.x == 0) { dinv[N] = 0.f; *gcount = 0u; }
}

// --- FUSED: blocks [0,GB) = MFMA GEMM (async gload_lds double-buffer, XOR-swizzled);
//     blocks [GB, GB+G_PART*NQUAD) = histo over (edge-partition g, node-quadrant). ---
__global__ void __launch_bounds__(256, 4) gemm_histo(const float* __restrict__ x,
                                                     const unsigned short* __restrict__ Wt,
                                                     unsigned short* __restrict__ hs, int N,
                                                     const int* __restrict__ col,
                                                     unsigned int* __restrict__ hist8,
                                                     int E, int GB) {
    __shared__ float xs[2][BM * BK];   // 32KB; histo path reuses as uint h[<=8192]

    if ((int)blockIdx.x >= GB) {
        // ---- histo quadrant block ----
        unsigned int* h = (unsigned int*)&xs[0][0];
        int NW = (N + 3) >> 2;
        int NWQ = (NW + NQUAD - 1) / NQUAD;
        int b = (int)blockIdx.x - GB;
        int g = b >> 2, quad = b & 3;
        int w0 = quad * NWQ, w1 = min(w0 + NWQ, NW);
        int nw = w1 - w0;
        for (int w = threadIdx.x; w < nw; w += 256) h[w] = 0u;
        __syncthreads();
        int P = (E + G_PART - 1) / G_PART;
        int e0 = g * P, e1 = min(e0 + P, E);
        for (int e = e0 + (int)threadIdx.x; e < e1; e += 256) {
            int c = col[e];
            int wq = c >> 2;
            if (wq >= w0 && wq < w1)
                atomicAdd(&h[wq - w0], 1u << ((c & 3) * 8));   // ds_add, no return
        }
        __syncthreads();
        unsigned int* dst = hist8 + (size_t)g * NW + w0;
        for (int w = threadIdx.x; w < nw; w += 256) dst[w] = h[w];
        return;
    }

    // ---- gemm block ----
    const int t = threadIdx.x;
    const int w = t >> 6, lane = t & 63;
    const int row0 = (int)blockIdx.x * BM;
    const int m = lane & 15, q = lane >> 4;

    // LDS row r: quad Lq holds global quad Lq ^ (r&7) (bank-conflict-free b128 reads);
    // gload_lds writes linearly -> inverse swizzle folded into global source address.
    auto stage = [&](int buf, int c0) {
#pragma unroll
        for (int j = 0; j < 4; ++j) {
            int i = w * 4 + j;
            int r = i * 4 + (lane >> 4);
            int rg = row0 + r; rg = rg < N ? rg : N - 1;   // tail clamp (dup reads, discarded)
            int k = ((lane & 15) ^ (r & 7)) << 2;
            const float* src = x + (size_t)rg * IN_CH + c0 * BK + k;
            __builtin_amdgcn_global_load_lds(
                (const __attribute__((address_space(1))) void*)src,
                (__attribute__((address_space(3))) void*)&xs[buf][i * 256], 16, 0, 0);
        }
    };

    const unsigned short* wr = Wt + (size_t)m * IN_CH + q * 8;
    const int pm = m & 7;
    const int rowbase = (w * 16 + m) * BK;
    f32x4 acc[4];
#pragma unroll
    for (int tt = 0; tt < 4; ++tt) acc[tt] = (f32x4){0.f, 0.f, 0.f, 0.f};

    stage(0, 0);
    int cur = 0;
    for (int c0 = 0; c0 < IN_CH / BK; ++c0) {   // 8 chunks
        __syncthreads();                         // buffer 'cur' ready; prev reads done
        if (c0 < IN_CH / BK - 1) stage(cur ^ 1, c0 + 1);   // async prefetch overlaps compute
#pragma unroll
        for (int s = 0; s < 2; ++s) {            // two K=32 MFMA steps per chunk
            int qi = s * 8 + q * 2;
            f32x4 a0 = *(const f32x4*)&xs[cur][rowbase + (((qi    ) ^ pm) << 2)];
            f32x4 a1 = *(const f32x4*)&xs[cur][rowbase + (((qi + 1) ^ pm) << 2)];
            short8 af;
            af[0] = (short)bf16bits(a0[0]); af[1] = (short)bf16bits(a0[1]);
            af[2] = (short)bf16bits(a0[2]); af[3] = (short)bf16bits(a0[3]);
            af[4] = (short)bf16bits(a1[0]); af[5] = (short)bf16bits(a1[1]);
            af[6] = (short)bf16bits(a1[2]); af[7] = (short)bf16bits(a1[3]);
#pragma unroll
            for (int tt = 0; tt < 4; ++tt) {
                short8 bf = *(const short8*)(wr + (size_t)tt * 16 * IN_CH + c0 * BK + s * 32);
                acc[tt] = __builtin_amdgcn_mfma_f32_16x16x32_bf16(af, bf, acc[tt], 0, 0, 0);
            }
        }
        cur ^= 1;
    }
    // C/D layout: col = lane&15, row (within 16) = q*4 + reg
    int rbase = row0 + w * 16 + q * 4;
#pragma unroll
    for (int r = 0; r < 4; ++r) {
        int row = rbase + r;
        if (row < N) {
#pragma unroll
            for (int tt = 0; tt < 4; ++tt)
                hs[(size_t)row * OUT_CH + tt * 16 + m] = bf16bits(acc[tt][r]);
        }
    }
}

// --- reduce + segment allocation: block = 64 words x all 128 planes (wave wv: 32 planes,
//     values in registers, static idx). Emits pre8 planes; last wave allocates rowptr
//     segments via ONE global atomic per wave (LLVM wave-coalesced) -- NO scan passes.
//     rowptr packs {cnt:8, base:24}; segments padded to mult of 8; also writes dinv. ---
__global__ void __launch_bounds__(256) reduce_kernel(const unsigned int* __restrict__ hist8,
                                                     unsigned int* __restrict__ pre8,
                                                     unsigned int* __restrict__ rowptr,
                                                     float* __restrict__ dinv,
                                                     unsigned int* __restrict__ gcount,
                                                     int N, int NW) {
    __shared__ unsigned int wsum[4][64];
    int lane = threadIdx.x & 63, wv = threadIdx.x >> 6;
    int w = (int)blockIdx.x * 64 + lane;
    bool act = w < NW;
    const unsigned int* hp = hist8 + (size_t)wv * 32 * NW + w;
    unsigned int v[32];
#pragma unroll
    for (int j = 0; j < 32; ++j) v[j] = act ? hp[(size_t)j * NW] : 0u;
    unsigned int s = 0;
#pragma unroll
    for (int j = 0; j < 32; ++j) s += v[j];
    wsum[wv][lane] = s;
    __syncthreads();
    unsigned int run = 0;
    for (int k = 0; k < wv; ++k) run += wsum[k][lane];
    if (act) {
        unsigned int* pp = pre8 + (size_t)wv * 32 * NW + w;
#pragma unroll
        for (int j = 0; j < 32; ++j) { pp[(size_t)j * NW] = run; run += v[j]; }
        if (wv == 3) {   // run = packed total degree of nodes 4w..4w+3 (carry-free)
            unsigned int d[4], p[4];
            unsigned int tp = 0;
#pragma unroll
            for (int j = 0; j < 4; ++j) {
                d[j] = (run >> (j * 8)) & 0xffu;
                p[j] = (d[j] + 7u) & ~7u;        // pad to mult of 8 (uint4-pair aligned)
                tp += p[j];
            }
            unsigned int base = atomicAdd(gcount, tp);
            int n0 = w * 4;
#pragma unroll
            for (int j = 0; j < 4; ++j) {
                if (n0 + j < N) {
                    rowptr[n0 + j] = base | (d[j] << 24);
                    dinv[n0 + j] = rsqrtf((float)(d[j] + 1u));
                }
                base += p[j];
            }
        }
    }
}

// --- fill: (partition, quadrant) blocks; LDS cursors preloaded with pre8 plane slice;
//     atomicAdd returns base+rank directly. pos = rowptr.base + byte cursor. ---
__global__ void __launch_bounds__(256, 8) fill_kernel(const int* __restrict__ ei,
                                                      const unsigned int* __restrict__ rowptr,
                                                      const unsigned int* __restrict__ pre8,
                                                      unsigned int* __restrict__ srcIdx,
                                                      int N, int E) {
    __shared__ unsigned int cur[NWQ_MAX];
    int NW = (N + 3) >> 2;
    int NWQ = (NW + NQUAD - 1) / NQUAD;
    int b = blockIdx.x;
    int g = b >> 2, quad = b & 3;
    int w0 = quad * NWQ, w1 = min(w0 + NWQ, NW);
    int nw = w1 - w0;
    const unsigned int* pre = pre8 + (size_t)g * NW + w0;
    for (int w = threadIdx.x; w < nw; w += 256) cur[w] = pre[w];
    __syncthreads();
    int P = (E + G_PART - 1) / G_PART;
    int e0 = g * P, e1 = min(e0 + P, E);
    for (int e = e0 + (int)threadIdx.x; e < e1; e += 256) {
        int c = ei[E + e];    // target
        int wq = c >> 2;
        if (wq >= w0 && wq < w1) {
            int r = ei[e];    // source
            int sh = (c & 3) * 8;
            unsigned int old = atomicAdd(&cur[wq - w0], 1u << sh);
            unsigned int pos = (rowptr[c] & 0xffffffu) + ((old >> sh) & 0xffu);
            srcIdx[pos] = (unsigned int)r;
        }
    }
}

// --- fused gather + self + bias + log_softmax. One wave/node. 16 lanes x uint2 per hs
//     row (4 ch/lane): 8 edges/iter with only 2 hs-load + 2 srcIdx-load instructions.
//     rowptr packs {cnt:8, base:24}; tail slots clamp to sentinel N (dinv[N]=0). ---
__global__ void __launch_bounds__(256) gather_kernel(const unsigned int* __restrict__ srcIdx,
                                                     const unsigned int* __restrict__ rowptr,
                                                     const float* __restrict__ dinv,
                                                     const unsigned short* __restrict__ hs,
                                                     const float* __restrict__ bias,
                                                     float* __restrict__ out, int N) {
    int node = (int)((blockIdx.x * (unsigned long long)blockDim.x + threadIdx.x) >> 6);
    int lane = threadIdx.x & 63;
    if (node >= N) return;
    int eg = lane >> 4;       // edge slot 0-3
    int sl = lane & 15;       // 8-byte chunk of row; channels 4*sl .. 4*sl+3
    unsigned int rp = rowptr[node];
    unsigned int start = rp & 0xffffffu;
    unsigned int cn = rp >> 24;
    unsigned int iters = (cn + 7u) >> 3;   // 8 edges/iter; segment padded to mult of 8
    const uint4* sp = (const uint4*)(srcIdx + start);
    unsigned int sent = (unsigned int)N;
    float a0 = 0.f, a1 = 0.f, a2 = 0.f, a3 = 0.f;
    for (unsigned int it = 0; it < iters; ++it) {
        uint4 iva = sp[2 * it];
        uint4 ivb = sp[2 * it + 1];
        unsigned int ia = eg == 0 ? iva.x : eg == 1 ? iva.y : eg == 2 ? iva.z : iva.w;
        unsigned int ib = eg == 0 ? ivb.x : eg == 1 ? ivb.y : eg == 2 ? ivb.z : ivb.w;
        unsigned int slot = it * 8u + (unsigned int)eg;
        ia = (slot      < cn) ? ia : sent;
        ib = (slot + 4u < cn) ? ib : sent;
        float da = dinv[ia], db = dinv[ib];
        uint2 ua = *(const uint2*)(hs + (size_t)ia * OUT_CH + 4 * sl);
        uint2 ub = *(const uint2*)(hs + (size_t)ib * OUT_CH + 4 * sl);
        a0 += bflo(ua.x) * da + bflo(ub.x) * db;
        a1 += bfhi(ua.x) * da + bfhi(ub.x) * db;
        a2 += bflo(ua.y) * da + bflo(ub.y) * db;
        a3 += bfhi(ua.y) * da + bfhi(ub.y) * db;
    }
    // reduce across the 4 edge-slot groups (lane bits 4,5)
    a0 += __shfl_xor(a0, 16, 64); a0 += __shfl_xor(a0, 32, 64);
    a1 += __shfl_xor(a1, 16, 64); a1 += __shfl_xor(a1, 32, 64);
    a2 += __shfl_xor(a2, 16, 64); a2 += __shfl_xor(a2, 32, 64);
    a3 += __shfl_xor(a3, 16, 64); a3 += __shfl_xor(a3, 32, 64);
    // self-loop + bias; whole sum scaled by dinv[node]
    float di = dinv[node];
    uint2 us = *(const uint2*)(hs + (size_t)node * OUT_CH + 4 * sl);
    a0 = fmaf(bflo(us.x), di, a0);
    a1 = fmaf(bfhi(us.x), di, a1);
    a2 = fmaf(bflo(us.y), di, a2);
    a3 = fmaf(bfhi(us.y), di, a3);
    float4 bb = *(const float4*)(bias + 4 * sl);
    float v0 = fmaf(a0, di, bb.x);
    float v1 = fmaf(a1, di, bb.y);
    float v2 = fmaf(a2, di, bb.z);
    float v3 = fmaf(a3, di, bb.w);
    // log_softmax over 64 channels: values replicated across eg groups -> reduce sl bits only
    float mx = fmaxf(fmaxf(v0, v1), fmaxf(v2, v3));
#pragma unroll
    for (int off = 8; off > 0; off >>= 1) mx = fmaxf(mx, __shfl_xor(mx, off, 64));
    float s = expf(v0 - mx) + expf(v1 - mx) + expf(v2 - mx) + expf(v3 - mx);
#pragma unroll
    for (int off = 8; off > 0; off >>= 1) s += __shfl_xor(s, off, 64);
    float ls = logf(s);
    if (eg == 0) {
        float4 o = {v0 - mx - ls, v1 - mx - ls, v2 - mx - ls, v3 - mx - ls};
        *(float4*)(out + (size_t)node * OUT_CH + 4 * sl) = o;
    }
}

extern "C" void kernel_launch(void* const* d_in, const int* in_sizes, int n_in,
                              void* d_out, int out_size, void* d_ws, size_t ws_size,
                              hipStream_t stream) {
    const float* x  = (const float*)d_in[0];
    const int*   ei = (const int*)d_in[1];
    const float* W  = (const float*)d_in[2];
    const float* b  = (const float*)d_in[3];
    float* out = (float*)d_out;

    const int N = in_sizes[0] / IN_CH;   // 100000
    const int E = in_sizes[1] / 2;       // 1600000
    const int NW = (N + 3) / 4;          // 25000 packed histogram words

    char* ws = (char*)d_ws;
    size_t o = 0;
    unsigned int* rowptr   = (unsigned int*)(ws + o); o += (size_t)N * 4;
    unsigned int* gcount   = (unsigned int*)(ws + o); o += 16;
    float*        dinv     = (float*)(ws + o);        o += ((size_t)(N + 1) * 4 + 15) & ~15ull;
    // hist8 (G_PART planes of NW words) aliases srcIdx: hist8 dead after reduce_kernel,
    // srcIdx written only in fill_kernel (after reduce). Region = max of the two.
    size_t histBytes   = (size_t)G_PART * NW * 4;
    size_t srcIdxBytes = ((size_t)E + 7u * (size_t)N + 64) * 4;
    unsigned int* hist8    = (unsigned int*)(ws + o);
    unsigned int* srcIdx   = (unsigned int*)(ws + o); o += (histBytes > srcIdxBytes ? histBytes : srcIdxBytes);
    unsigned int* pre8     = (unsigned int*)(ws + o); o += histBytes;
    unsigned short* Wt     = (unsigned short*)(ws + o); o += (size_t)IN_CH * OUT_CH * 2;
    unsigned short* hs     = (unsigned short*)(ws + o); o += (size_t)(N + 1) * OUT_CH * 2;

    const int GB = (N + BM - 1) / BM;             // gemm blocks = 1563
    const int HB = G_PART * NQUAD;                // histo/fill blocks = 512

    prep_kernel<<<129, 256, 0, stream>>>(W, Wt, hs, dinv, gcount, N);
    gemm_histo<<<GB + HB, 256, 0, stream>>>(x, Wt, hs, N, ei + E, hist8, E, GB);
    reduce_kernel<<<(NW + 63) / 64, 256, 0, stream>>>(hist8, pre8, rowptr, dinv, gcount, N, NW);
    fill_kernel<<<HB, 256, 0, stream>>>(ei, rowptr, pre8, srcIdx, N, E);
    gather_kernel<<<((size_t)N * 64 + 255) / 256, 256, 0, stream>>>(srcIdx, rowptr, dinv, hs, b, out, N);
}